// Round 7
// baseline (2000.456 us; speedup 1.0000x reference)
//
#include <hip/hip_runtime.h>
#include <hip/hip_fp16.h>
#include <math.h>

// ---------------------------------------------------------------------------
// GCN autoencoder: 4 layers (12->16->8->16->12), N=200K nodes, E=5M edges.
//
// Round 7: drop the full CSR (csr_bucket + col) entirely. The bucket-sorted
// `binned` records ((src<<10)|local_dst, 1024 dst nodes per bucket) are
// gathered EDGE-PARALLEL: one WG per (bucket, quarter-segment) accumulates
// dis-scaled source features into an LDS accumulator (odd stride, LDS float
// atomics), then flushes dis[dst]*acc to agg with coalesced global atomics.
// Uniform per-thread work, coalesced record reads, no degree-tail divergence.
// Degree comes from a cheap LDS-count pass; transform self-inits agg
// (ping-pong a/b).
// ---------------------------------------------------------------------------

#define NPB 1024               // nodes per bucket; bucket id = dst >> 10
#define MAX_NB 256             // supports N <= 262144
#define BIN_CHUNK 6144         // edges per workgroup in bin_kernel
#define EPT (BIN_CHUNK / 256)  // edges per thread in bin_kernel (24)
#define SEG 4                  // segments per bucket in gather/deg kernels

__global__ __launch_bounds__(256) void hist_kernel(const int* __restrict__ dst,
                                                   int* __restrict__ bucket_cnt,
                                                   int E, int NB) {
    __shared__ int h[MAX_NB];
    for (int t = threadIdx.x; t < NB; t += 256) h[t] = 0;
    __syncthreads();
    int stride = gridDim.x * 256;
    for (int e = blockIdx.x * 256 + threadIdx.x; e < E; e += stride)
        atomicAdd(&h[dst[e] >> 10], 1);
    __syncthreads();
    for (int t = threadIdx.x; t < NB; t += 256)
        if (h[t]) atomicAdd(&bucket_cnt[t], h[t]);
}

__global__ __launch_bounds__(1024) void bscan_kernel(const int* __restrict__ bucket_cnt,
                                                     int* __restrict__ bucket_ptr,
                                                     int* __restrict__ bucket_cur,
                                                     int NB, int E) {
    __shared__ int s[1024];
    int v = (threadIdx.x < (unsigned)NB) ? bucket_cnt[threadIdx.x] : 0;
    s[threadIdx.x] = v;
    __syncthreads();
    for (int off = 1; off < 1024; off <<= 1) {
        int t = (threadIdx.x >= (unsigned)off) ? s[threadIdx.x - off] : 0;
        __syncthreads();
        s[threadIdx.x] += t;
        __syncthreads();
    }
    int excl = s[threadIdx.x] - v;
    if (threadIdx.x < (unsigned)NB) {
        bucket_ptr[threadIdx.x] = excl;
        bucket_cur[threadIdx.x] = excl;
    }
    if (threadIdx.x == 0) bucket_ptr[NB] = E;
}

// Block-level LDS counting sort of a 6144-edge chunk:
//   hist -> block scan -> reserve global runs (1 atomic/bucket) ->
//   LDS scatter into bucket order -> coalesced flush (binary search
//   slot -> bucket). Records: (src<<10)|local_dst.
__global__ __launch_bounds__(256) void bin_kernel(const int* __restrict__ src,
                                                  const int* __restrict__ dst,
                                                  int* __restrict__ bucket_cur,
                                                  unsigned int* __restrict__ binned,
                                                  int E, int NB) {
    __shared__ int h[MAX_NB];          // hist, then reused as scatter cursor
    __shared__ int scl[MAX_NB + 1];    // block-local exclusive offsets
    __shared__ int base[MAX_NB];       // global run bases
    __shared__ int sscan[256];
    __shared__ unsigned int stage[BIN_CHUNK];  // 24 KB
    int cbeg = blockIdx.x * BIN_CHUNK;
    int cend = min(cbeg + BIN_CHUNK, E);
    int chunk_n = cend - cbeg;
    int tid = threadIdx.x;

    for (int t = tid; t < NB; t += 256) h[t] = 0;
    __syncthreads();
    int myd[EPT];
#pragma unroll
    for (int j = 0; j < EPT; j++) {
        int e = cbeg + tid + j * 256;
        if (e < cend) {
            myd[j] = dst[e];
            atomicAdd(&h[myd[j] >> 10], 1);
        }
    }
    __syncthreads();
    int v = (tid < NB) ? h[tid] : 0;
    sscan[tid] = v;
    __syncthreads();
    for (int off = 1; off < 256; off <<= 1) {
        int t = (tid >= off) ? sscan[tid - off] : 0;
        __syncthreads();
        sscan[tid] += t;
        __syncthreads();
    }
    if (tid < NB) {
        scl[tid] = sscan[tid] - v;
        base[tid] = v ? atomicAdd(&bucket_cur[tid], v) : 0;
    }
    if (tid == 0) scl[NB] = chunk_n;
    __syncthreads();
    for (int t = tid; t < NB; t += 256) h[t] = 0;  // reuse as cursor
    __syncthreads();
#pragma unroll
    for (int j = 0; j < EPT; j++) {
        int e = cbeg + tid + j * 256;
        if (e < cend) {
            int d = myd[j];
            int bkt = d >> 10;
            int pos = scl[bkt] + atomicAdd(&h[bkt], 1);
            stage[pos] = ((unsigned)src[e] << 10) | (unsigned)(d & 1023);
        }
    }
    __syncthreads();
    for (int k = tid; k < chunk_n; k += 256) {
        int lo = 0, hi = NB;  // scl[lo] <= k < scl[hi]
        while (hi - lo > 1) {
            int mid = (lo + hi) >> 1;
            if (scl[mid] <= k) lo = mid; else hi = mid;
        }
        binned[base[lo] + (k - scl[lo])] = stage[k];
    }
}

// Per-(bucket, segment): count local-dst occurrences in LDS, flush to deg.
__global__ __launch_bounds__(256) void deg_seg_kernel(
    const unsigned int* __restrict__ binned, const int* __restrict__ bucket_ptr,
    int* __restrict__ deg, int N) {
    __shared__ int cnt[NPB];
    int b = blockIdx.x >> 2;
    int seg = blockIdx.x & (SEG - 1);
    int beg = bucket_ptr[b], end = bucket_ptr[b + 1];
    int bsize = end - beg;
    int sbeg = beg + (int)(((long long)bsize * seg) / SEG);
    int send = beg + (int)(((long long)bsize * (seg + 1)) / SEG);
    int tid = threadIdx.x;
    for (int t = tid; t < NPB; t += 256) cnt[t] = 0;
    __syncthreads();
    for (int k = sbeg + tid; k < send; k += 256)
        atomicAdd(&cnt[binned[k] & 1023u], 1);
    __syncthreads();
    int nbase = b << 10;
    int nlocal = min(NPB, N - nbase);
    for (int t = tid; t < nlocal; t += 256)
        if (cnt[t]) atomicAdd(&deg[nbase + t], cnt[t]);
}

__global__ void dis_kernel(const int* __restrict__ deg, float* __restrict__ dis, int N) {
    int i = blockIdx.x * blockDim.x + threadIdx.x;
    if (i < N) dis[i] = 1.0f / sqrtf((float)(deg[i] + 1));  // +1 self-loop
}

// PREACT: 0 = raw input (layer 1), 1 = bias + relu, 2 = bias only
// Writes fp16 xls chunk tables AND self-initializes agg = xls * dis (fp32).
template <int IN, int OUT, int C, int PREACT>
__global__ __launch_bounds__(256) void transform_kernel(
    const float* __restrict__ hin, const float* __restrict__ bias_prev,
    const float* __restrict__ W, const float* __restrict__ dis,
    __half* __restrict__ xls, float* __restrict__ agg, int N) {
    __shared__ float sW[IN * OUT];
    __shared__ float sB[IN];
    for (int t = threadIdx.x; t < IN * OUT; t += blockDim.x) sW[t] = W[t];
    if (PREACT != 0) {
        for (int t = threadIdx.x; t < IN; t += blockDim.x) sB[t] = bias_prev[t];
    }
    __syncthreads();
    int i = blockIdx.x * blockDim.x + threadIdx.x;
    if (i >= N) return;

    float h[IN];
#pragma unroll
    for (int k = 0; k < IN; k++) {
        float v = hin[i * IN + k];
        if (PREACT != 0) {
            v += sB[k];
            if (PREACT == 1) v = fmaxf(v, 0.0f);
        }
        h[k] = v;
    }
    float d = dis[i];
    float o[OUT];
#pragma unroll
    for (int f = 0; f < OUT; f++) {
        float acc = 0.0f;
#pragma unroll
        for (int k = 0; k < IN; k++) acc = fmaf(h[k], sW[k * OUT + f], acc);
        o[f] = acc * d;                       // xls = (h@W) * dis_i
        agg[(size_t)i * OUT + f] = o[f] * d;  // self-loop: (h@W) * dis_i^2
    }
    constexpr int NCH = OUT / C;
    constexpr int P = C / 2;
    __half2* x2 = (__half2*)xls;
#pragma unroll
    for (int c = 0; c < NCH; c++) {
#pragma unroll
        for (int k = 0; k < P; k++) {
            x2[(size_t)c * N * P + (size_t)i * P + k] =
                __floats2half2_rn(o[c * C + 2 * k], o[c * C + 2 * k + 1]);
        }
    }
}

// Edge-parallel gather over one C-feature chunk table (L2-resident).
// One WG per (bucket, quarter-segment): coalesced record reads, one 16B/12B
// table load per edge, LDS float-atomic accumulation at odd stride (C+1),
// then coalesced global-atomic flush of dis[dst]*acc into agg.
template <int C, int F, int COFF>
__global__ __launch_bounds__(256) void gather_seg_kernel(
    const unsigned int* __restrict__ binned, const int* __restrict__ bucket_ptr,
    const float* __restrict__ dis, const __half* __restrict__ xls,
    float* __restrict__ agg, int N) {
    constexpr int P = C / 2;
    constexpr int STRIDE = C + 1;  // odd stride -> LDS banks spread
    __shared__ float acc[NPB * STRIDE];
    int b = blockIdx.x >> 2;
    int seg = blockIdx.x & (SEG - 1);
    int beg = bucket_ptr[b], end = bucket_ptr[b + 1];
    int bsize = end - beg;
    int sbeg = beg + (int)(((long long)bsize * seg) / SEG);
    int send = beg + (int)(((long long)bsize * (seg + 1)) / SEG);
    int tid = threadIdx.x;
    for (int t = tid; t < NPB * STRIDE; t += 256) acc[t] = 0.0f;
    __syncthreads();
    const __half2* x2 = (const __half2*)xls;
    int k = sbeg + tid;
    // unroll x2: two records in flight per iteration
    for (; k + 256 < send; k += 512) {
        unsigned r0 = binned[k];
        unsigned r1 = binned[k + 256];
        int s0 = (int)(r0 >> 10), l0 = (int)(r0 & 1023u);
        int s1 = (int)(r1 >> 10), l1 = (int)(r1 & 1023u);
        __half2 t0[P], t1[P];
#pragma unroll
        for (int j = 0; j < P; j++) t0[j] = x2[(size_t)s0 * P + j];
#pragma unroll
        for (int j = 0; j < P; j++) t1[j] = x2[(size_t)s1 * P + j];
        float* a0 = &acc[l0 * STRIDE];
        float* a1 = &acc[l1 * STRIDE];
#pragma unroll
        for (int j = 0; j < P; j++) {
            float2 v = __half22float2(t0[j]);
            atomicAdd(a0 + 2 * j, v.x);
            atomicAdd(a0 + 2 * j + 1, v.y);
        }
#pragma unroll
        for (int j = 0; j < P; j++) {
            float2 v = __half22float2(t1[j]);
            atomicAdd(a1 + 2 * j, v.x);
            atomicAdd(a1 + 2 * j + 1, v.y);
        }
    }
    if (k < send) {
        unsigned r0 = binned[k];
        int s0 = (int)(r0 >> 10), l0 = (int)(r0 & 1023u);
        float* a0 = &acc[l0 * STRIDE];
#pragma unroll
        for (int j = 0; j < P; j++) {
            float2 v = __half22float2(x2[(size_t)s0 * P + j]);
            atomicAdd(a0 + 2 * j, v.x);
            atomicAdd(a0 + 2 * j + 1, v.y);
        }
    }
    __syncthreads();
    int nbase = b << 10;
    int nlocal = min(NPB, N - nbase);
    for (int t = tid; t < nlocal * C; t += 256) {
        int loc = t / C;
        int f = t - loc * C;
        float v = acc[loc * STRIDE + f];
        if (v != 0.0f)
            atomicAdd(&agg[(size_t)(nbase + loc) * F + COFF + f],
                      dis[nbase + loc] * v);
    }
}

__global__ void final_kernel(const float* __restrict__ agg,
                             const float* __restrict__ b,
                             float* __restrict__ out, int total, int F) {
    int idx = blockIdx.x * blockDim.x + threadIdx.x;
    if (idx < total) {
        int f = idx % F;
        float v = agg[idx] + b[f];
        out[idx] = 1.0f / (1.0f + expf(-v));
    }
}

static inline size_t align_up(size_t v, size_t a) { return (v + a - 1) & ~(a - 1); }

extern "C" void kernel_launch(void* const* d_in, const int* in_sizes, int n_in,
                              void* d_out, int out_size, void* d_ws, size_t ws_size,
                              hipStream_t stream) {
    const float* x  = (const float*)d_in[0];
    const int*   ei = (const int*)d_in[1];
    const float* W1 = (const float*)d_in[2];
    const float* b1 = (const float*)d_in[3];
    const float* W2 = (const float*)d_in[4];
    const float* b2 = (const float*)d_in[5];
    const float* W3 = (const float*)d_in[6];
    const float* b3 = (const float*)d_in[7];
    const float* W4 = (const float*)d_in[8];
    const float* b4 = (const float*)d_in[9];
    float* out = (float*)d_out;

    const int N = in_sizes[0] / 12;
    const int E = in_sizes[1] / 2;
    const int* src = ei;       // edge_index[0]
    const int* dst = ei + E;   // edge_index[1]
    const int NB = (N + NPB - 1) / NPB;  // 196

    // Workspace carve-up (~54 MB)
    char* ws = (char*)d_ws;
    size_t off = 0;
    int* bucket_cnt = (int*)(ws + off);   off = align_up(off + (size_t)NB * 4, 256);
    int* bucket_ptr = (int*)(ws + off);   off = align_up(off + (size_t)(NB + 1) * 4, 256);
    int* bucket_cur = (int*)(ws + off);   off = align_up(off + (size_t)NB * 4, 256);
    int* deg = (int*)(ws + off);          off = align_up(off + (size_t)N * 4, 256);
    float* dis = (float*)(ws + off);      off = align_up(off + (size_t)N * 4, 256);
    unsigned int* binned = (unsigned int*)(ws + off); off = align_up(off + (size_t)E * 4, 256);
    __half* xls = (__half*)(ws + off);    off = align_up(off + (size_t)N * 16 * 2, 256);
    float* agg_a = (float*)(ws + off);    off = align_up(off + (size_t)N * 16 * 4, 256);
    float* agg_b = (float*)(ws + off);    off = align_up(off + (size_t)N * 16 * 4, 256);
    (void)ws_size; (void)n_in; (void)out_size;

    const int B = 256;
    auto blocks = [&](long long n) { return (int)((n + B - 1) / B); };

    // --- build: bucket-sort edges + degrees ------------------------------
    hipMemsetAsync(bucket_cnt, 0, (size_t)NB * sizeof(int), stream);
    hipMemsetAsync(deg, 0, (size_t)N * sizeof(int), stream);
    hist_kernel<<<512, B, 0, stream>>>(dst, bucket_cnt, E, NB);
    bscan_kernel<<<1, 1024, 0, stream>>>(bucket_cnt, bucket_ptr, bucket_cur, NB, E);
    bin_kernel<<<(E + BIN_CHUNK - 1) / BIN_CHUNK, B, 0, stream>>>(src, dst, bucket_cur, binned, E, NB);
    deg_seg_kernel<<<NB * SEG, B, 0, stream>>>(binned, bucket_ptr, deg, N);
    dis_kernel<<<blocks(N), B, 0, stream>>>(deg, dis, N);

    // Chunk-table bases (half units): chunk c of size C lives at c*N*C
    __half* x_c0 = xls;
    __half* x_c8 = xls + (size_t)N * 8;  // second chunk for C=8 layers
    __half* x_c6 = xls + (size_t)N * 6;  // second chunk for C=6 layer

    // --- Layer 1: x(12) @ W1 -> 16 (chunks 2x8) --------------------------
    transform_kernel<12, 16, 8, 0><<<blocks(N), B, 0, stream>>>(x, nullptr, W1, dis, xls, agg_a, N);
    gather_seg_kernel<8, 16, 0><<<NB * SEG, B, 0, stream>>>(binned, bucket_ptr, dis, x_c0, agg_a, N);
    gather_seg_kernel<8, 16, 8><<<NB * SEG, B, 0, stream>>>(binned, bucket_ptr, dis, x_c8, agg_a, N);

    // --- Layer 2: relu(agg_a + b1)(16) @ W2 -> 8 (1x8) -------------------
    transform_kernel<16, 8, 8, 1><<<blocks(N), B, 0, stream>>>(agg_a, b1, W2, dis, xls, agg_b, N);
    gather_seg_kernel<8, 8, 0><<<NB * SEG, B, 0, stream>>>(binned, bucket_ptr, dis, x_c0, agg_b, N);

    // --- Layer 3: (agg_b + b2)(8) @ W3 -> 16 (2x8, no relu) --------------
    transform_kernel<8, 16, 8, 2><<<blocks(N), B, 0, stream>>>(agg_b, b2, W3, dis, xls, agg_a, N);
    gather_seg_kernel<8, 16, 0><<<NB * SEG, B, 0, stream>>>(binned, bucket_ptr, dis, x_c0, agg_a, N);
    gather_seg_kernel<8, 16, 8><<<NB * SEG, B, 0, stream>>>(binned, bucket_ptr, dis, x_c8, agg_a, N);

    // --- Layer 4: relu(agg_a + b3)(16) @ W4 -> 12 (chunks 2x6) -----------
    transform_kernel<16, 12, 6, 1><<<blocks(N), B, 0, stream>>>(agg_a, b3, W4, dis, xls, agg_b, N);
    gather_seg_kernel<6, 12, 0><<<NB * SEG, B, 0, stream>>>(binned, bucket_ptr, dis, x_c0, agg_b, N);
    gather_seg_kernel<6, 12, 6><<<NB * SEG, B, 0, stream>>>(binned, bucket_ptr, dis, x_c6, agg_b, N);

    // --- Epilogue: sigmoid(agg_b + b4) -> out ----------------------------
    final_kernel<<<blocks((long long)N * 12), B, 0, stream>>>(agg_b, b4, out, N * 12, 12);
}

// Round 8
// 493.938 us; speedup vs baseline: 4.0500x; 4.0500x over previous
//
#include <hip/hip_runtime.h>
#include <hip/hip_fp16.h>
#include <math.h>

// ---------------------------------------------------------------------------
// GCN autoencoder: 4 layers (12->16->8->16->12), N=200K nodes, E=5M edges.
//
// Round 8: revert to the round-6 structure (LDS-sort bin + csr_bucket +
// thread-pair pull gather; R7's LDS-float-atomic gather was 5x worse).
// Changes vs R6:
//  * bin_kernel: 512 threads/block (same 6144-edge chunk) -> 2x waves/CU
//    (was grid-starved at 22% occupancy).
//  * per-layer chunk-pair gathers merged into ONE kernel, chunk picked by
//    (blockIdx&7)>=4 -> with round-robin block->XCD dispatch each XCD's L2
//    holds only its own 3.2 MB chunk table; correctness independent of the
//    mapping. Halves gather launches, doubles resident waves per pass.
// ---------------------------------------------------------------------------

#define NPB 1024               // nodes per bucket; bucket id = dst >> 10
#define MAX_NB 256             // supports N <= 262144
#define BIN_CHUNK 6144         // edges per workgroup in bin_kernel
#define BIN_TH 512             // threads per workgroup in bin_kernel
#define EPT (BIN_CHUNK / BIN_TH)  // edges per thread (12)
#define MAXB 14336             // LDS col staging (half-bucket avg ~12800)

__global__ __launch_bounds__(256) void hist_kernel(const int* __restrict__ dst,
                                                   int* __restrict__ bucket_cnt,
                                                   int E, int NB) {
    __shared__ int h[MAX_NB];
    for (int t = threadIdx.x; t < NB; t += 256) h[t] = 0;
    __syncthreads();
    int stride = gridDim.x * 256;
    for (int e = blockIdx.x * 256 + threadIdx.x; e < E; e += stride)
        atomicAdd(&h[dst[e] >> 10], 1);
    __syncthreads();
    for (int t = threadIdx.x; t < NB; t += 256)
        if (h[t]) atomicAdd(&bucket_cnt[t], h[t]);
}

__global__ __launch_bounds__(1024) void bscan_kernel(const int* __restrict__ bucket_cnt,
                                                     int* __restrict__ bucket_ptr,
                                                     int* __restrict__ bucket_cur,
                                                     int* __restrict__ row_ptr,
                                                     int NB, int N, int E) {
    __shared__ int s[1024];
    int v = (threadIdx.x < (unsigned)NB) ? bucket_cnt[threadIdx.x] : 0;
    s[threadIdx.x] = v;
    __syncthreads();
    for (int off = 1; off < 1024; off <<= 1) {
        int t = (threadIdx.x >= (unsigned)off) ? s[threadIdx.x - off] : 0;
        __syncthreads();
        s[threadIdx.x] += t;
        __syncthreads();
    }
    int excl = s[threadIdx.x] - v;
    if (threadIdx.x < (unsigned)NB) {
        bucket_ptr[threadIdx.x] = excl;
        bucket_cur[threadIdx.x] = excl;
    }
    if (threadIdx.x == 0) { bucket_ptr[NB] = E; row_ptr[N] = E; }
}

// Block-level LDS counting sort of a 6144-edge chunk (512 threads):
//   hist -> block scan (first 256 threads) -> reserve global runs
//   (1 atomic/bucket) -> LDS scatter into bucket order -> coalesced flush.
// Records: (src<<10)|local_dst.
__global__ __launch_bounds__(BIN_TH) void bin_kernel(const int* __restrict__ src,
                                                     const int* __restrict__ dst,
                                                     int* __restrict__ bucket_cur,
                                                     unsigned int* __restrict__ binned,
                                                     int E, int NB) {
    __shared__ int h[MAX_NB];          // hist, then reused as scatter cursor
    __shared__ int scl[MAX_NB + 1];    // block-local exclusive offsets
    __shared__ int base[MAX_NB];       // global run bases
    __shared__ int sscan[256];
    __shared__ unsigned int stage[BIN_CHUNK];  // 24 KB
    int cbeg = blockIdx.x * BIN_CHUNK;
    int cend = min(cbeg + BIN_CHUNK, E);
    int chunk_n = cend - cbeg;
    int tid = threadIdx.x;

    for (int t = tid; t < NB; t += BIN_TH) h[t] = 0;
    __syncthreads();
    int myd[EPT];
#pragma unroll
    for (int j = 0; j < EPT; j++) {
        int e = cbeg + tid + j * BIN_TH;
        if (e < cend) {
            myd[j] = dst[e];
            atomicAdd(&h[myd[j] >> 10], 1);
        }
    }
    __syncthreads();
    // exclusive scan of h[0..NB) using the first 256 threads (NB <= 256);
    // ALL threads execute the same barrier sequence.
    int v = (tid < NB) ? h[tid] : 0;
    if (tid < 256) sscan[tid] = v;
    __syncthreads();
    for (int off = 1; off < 256; off <<= 1) {
        int t = (tid >= off && tid < 256) ? sscan[tid - off] : 0;
        __syncthreads();
        if (tid < 256) sscan[tid] += t;
        __syncthreads();
    }
    if (tid < NB) {
        scl[tid] = sscan[tid] - v;
        base[tid] = v ? atomicAdd(&bucket_cur[tid], v) : 0;
    }
    if (tid == 0) scl[NB] = chunk_n;
    __syncthreads();
    for (int t = tid; t < NB; t += BIN_TH) h[t] = 0;  // reuse as cursor
    __syncthreads();
#pragma unroll
    for (int j = 0; j < EPT; j++) {
        int e = cbeg + tid + j * BIN_TH;
        if (e < cend) {
            int d = myd[j];
            int bkt = d >> 10;
            int pos = scl[bkt] + atomicAdd(&h[bkt], 1);
            stage[pos] = ((unsigned)src[e] << 10) | (unsigned)(d & 1023);
        }
    }
    __syncthreads();
    // coalesced flush: slot k -> bucket via binary search on scl
    for (int k = tid; k < chunk_n; k += BIN_TH) {
        int lo = 0, hi = NB;  // scl[lo] <= k < scl[hi]
        while (hi - lo > 1) {
            int mid = (lo + hi) >> 1;
            if (scl[mid] <= k) lo = mid; else hi = mid;
        }
        binned[base[lo] + (k - scl[lo])] = stage[k];
    }
}

// One WG per HALF bucket (512 nodes): filter the bucket's records by the
// local-id high bit, per-node count + scan in LDS, emit row_ptr/dis
// (sequential), scatter src into LDS colbuf, flush coalesced.
__global__ __launch_bounds__(512) void csr_bucket_kernel(
    const unsigned int* __restrict__ binned,
    const int* __restrict__ bucket_ptr,
    int* __restrict__ row_ptr, float* __restrict__ dis,
    int* __restrict__ col, int N) {
    __shared__ int cnt[512];
    __shared__ int cur[512];
    __shared__ int colbuf[MAXB];
    __shared__ int c0;      // records of this bucket with local < 512
    __shared__ int tot_s;   // records belonging to this half
    int b = blockIdx.x >> 1;
    int half = blockIdx.x & 1;
    int nbase = b * NPB + half * 512;
    int nlocal = min(512, N - nbase);
    int beg = bucket_ptr[b];
    int end = bucket_ptr[b + 1];
    int bsize = end - beg;
    int tid = threadIdx.x;

    cnt[tid] = 0;
    if (tid == 0) c0 = 0;
    __syncthreads();
    for (int k = tid; k < bsize; k += 512) {
        unsigned rec = binned[beg + k];
        int loc = (int)(rec & 1023u);
        if ((loc >> 9) == half) atomicAdd(&cnt[loc & 511], 1);
        unsigned long long m = __ballot(loc < 512);
        if ((tid & 63) == 0) atomicAdd(&c0, (int)__popcll(m));
    }
    __syncthreads();
    int v = cnt[tid];
    cur[tid] = v;
    __syncthreads();
    for (int off = 1; off < 512; off <<= 1) {
        int t = (tid >= off) ? cur[tid - off] : 0;
        __syncthreads();
        cur[tid] += t;
        __syncthreads();
    }
    int excl = cur[tid] - v;
    if (tid == 511) tot_s = cur[511];
    __syncthreads();
    int base_col = beg + (half ? c0 : 0);
    int tot = tot_s;
    if (tid < nlocal) {
        row_ptr[nbase + tid] = base_col + excl;
        dis[nbase + tid] = 1.0f / sqrtf((float)(v + 1));  // +1 self-loop
    }
    __syncthreads();
    cur[tid] = excl;
    __syncthreads();
    if (tot <= MAXB) {
        for (int k = tid; k < bsize; k += 512) {
            unsigned rec = binned[beg + k];
            int loc = (int)(rec & 1023u);
            if ((loc >> 9) == half) {
                int pos = atomicAdd(&cur[loc & 511], 1);
                colbuf[pos] = (int)(rec >> 10);
            }
        }
        __syncthreads();
        for (int k = tid; k < tot; k += 512) col[base_col + k] = colbuf[k];
    } else {  // statistical impossibility for this input; correctness fallback
        for (int k = tid; k < bsize; k += 512) {
            unsigned rec = binned[beg + k];
            int loc = (int)(rec & 1023u);
            if ((loc >> 9) == half) {
                int pos = atomicAdd(&cur[loc & 511], 1);
                col[base_col + pos] = (int)(rec >> 10);
            }
        }
    }
}

// PREACT: 0 = raw input (layer 1), 1 = bias + relu, 2 = bias only
// Writes fp16 xls split into OUT/C chunk tables of C features each.
template <int IN, int OUT, int C, int PREACT>
__global__ __launch_bounds__(256) void transform_kernel(
    const float* __restrict__ hin, const float* __restrict__ bias_prev,
    const float* __restrict__ W, const float* __restrict__ dis,
    __half* __restrict__ xls, int N) {
    __shared__ float sW[IN * OUT];
    __shared__ float sB[IN];
    for (int t = threadIdx.x; t < IN * OUT; t += blockDim.x) sW[t] = W[t];
    if (PREACT != 0) {
        for (int t = threadIdx.x; t < IN; t += blockDim.x) sB[t] = bias_prev[t];
    }
    __syncthreads();
    int i = blockIdx.x * blockDim.x + threadIdx.x;
    if (i >= N) return;

    float h[IN];
#pragma unroll
    for (int k = 0; k < IN; k++) {
        float v = hin[i * IN + k];
        if (PREACT != 0) {
            v += sB[k];
            if (PREACT == 1) v = fmaxf(v, 0.0f);
        }
        h[k] = v;
    }
    float d = dis[i];
    float o[OUT];
#pragma unroll
    for (int f = 0; f < OUT; f++) {
        float acc = 0.0f;
#pragma unroll
        for (int k = 0; k < IN; k++) acc = fmaf(h[k], sW[k * OUT + f], acc);
        o[f] = acc * d;  // pre-scaled by dis[i]
    }
    constexpr int NCH = OUT / C;
    constexpr int P = C / 2;
    __half2* x2 = (__half2*)xls;
#pragma unroll
    for (int c = 0; c < NCH; c++) {
#pragma unroll
        for (int k = 0; k < P; k++) {
            x2[(size_t)c * N * P + (size_t)i * P + k] =
                __floats2half2_rn(o[c * C + 2 * k], o[c * C + 2 * k + 1]);
        }
    }
}

// Pull gather body shared by single/merged kernels: lane-pair per node,
// unroll x4 (8-edge stride per lane), partials combined via __shfl_xor.
template <int C, int F>
__device__ __forceinline__ void gather_body(
    int i, int p, const int* __restrict__ row_ptr, const int* __restrict__ col,
    const float* __restrict__ dis, const __half2* __restrict__ x2,
    float* __restrict__ agg, int coff) {
    constexpr int P = C / 2;
    float2 acc[P];
#pragma unroll
    for (int k = 0; k < P; k++) {
        if (p == 0) acc[k] = __half22float2(x2[(size_t)i * P + k]);  // self-loop
        else acc[k] = make_float2(0.0f, 0.0f);
    }
    int beg = row_ptr[i];
    int end = row_ptr[i + 1];
    int e = beg + p;
    for (; e + 6 < end; e += 8) {
        int c0 = col[e], c1 = col[e + 2], c2 = col[e + 4], c3 = col[e + 6];
        __half2 t0[P], t1[P], t2[P], t3[P];
#pragma unroll
        for (int k = 0; k < P; k++) t0[k] = x2[(size_t)c0 * P + k];
#pragma unroll
        for (int k = 0; k < P; k++) t1[k] = x2[(size_t)c1 * P + k];
#pragma unroll
        for (int k = 0; k < P; k++) t2[k] = x2[(size_t)c2 * P + k];
#pragma unroll
        for (int k = 0; k < P; k++) t3[k] = x2[(size_t)c3 * P + k];
#pragma unroll
        for (int k = 0; k < P; k++) {
            float2 a = __half22float2(t0[k]), bb = __half22float2(t1[k]);
            float2 cc = __half22float2(t2[k]), dd = __half22float2(t3[k]);
            acc[k].x += (a.x + bb.x) + (cc.x + dd.x);
            acc[k].y += (a.y + bb.y) + (cc.y + dd.y);
        }
    }
    for (; e < end; e += 2) {
        int c = col[e];
#pragma unroll
        for (int k = 0; k < P; k++) {
            float2 vv = __half22float2(x2[(size_t)c * P + k]);
            acc[k].x += vv.x;
            acc[k].y += vv.y;
        }
    }
#pragma unroll
    for (int k = 0; k < P; k++) {
        acc[k].x += __shfl_xor(acc[k].x, 1);
        acc[k].y += __shfl_xor(acc[k].y, 1);
    }
    float d = dis[i];
    float2* ap = (float2*)(agg + (size_t)i * F + coff);
#pragma unroll
    for (int k = 0; k < P; k++) {
        if ((k & 1) == p) ap[k] = make_float2(acc[k].x * d, acc[k].y * d);
    }
}

// Single-chunk gather (layer 2).
template <int C, int F, int COFF>
__global__ __launch_bounds__(256) void gather_kernel(
    const int* __restrict__ row_ptr, const int* __restrict__ col,
    const float* __restrict__ dis, const __half* __restrict__ xls,
    float* __restrict__ agg, int N) {
    int tid = blockIdx.x * blockDim.x + threadIdx.x;
    int i = tid >> 1;
    int p = tid & 1;
    if (i >= N) return;
    gather_body<C, F>(i, p, row_ptr, col, dis, (const __half2*)xls, agg, COFF);
}

// Merged two-chunk gather: chunk = (blockIdx&7)>=4. With round-robin
// block->XCD dispatch each XCD's L2 caches only one 3.2 MB chunk table;
// coverage (and thus correctness) does not depend on the mapping.
template <int C, int F>
__global__ __launch_bounds__(256) void gather2_kernel(
    const int* __restrict__ row_ptr, const int* __restrict__ col,
    const float* __restrict__ dis, const __half* __restrict__ x0,
    const __half* __restrict__ x1, float* __restrict__ agg, int N) {
    int grp = blockIdx.x >> 3;
    int sub = blockIdx.x & 7;
    int chunk = sub >> 2;
    int range = (grp << 2) + (sub & 3);
    int t2 = range * 256 + (int)threadIdx.x;
    int i = t2 >> 1;
    int p = t2 & 1;
    if (i >= N) return;
    const __half2* x2 = (const __half2*)(chunk ? x1 : x0);
    gather_body<C, F>(i, p, row_ptr, col, dis, x2, agg, chunk ? C : 0);
}

__global__ void final_kernel(const float* __restrict__ agg,
                             const float* __restrict__ b,
                             float* __restrict__ out, int total, int F) {
    int idx = blockIdx.x * blockDim.x + threadIdx.x;
    if (idx < total) {
        int f = idx % F;
        float v = agg[idx] + b[f];
        out[idx] = 1.0f / (1.0f + expf(-v));
    }
}

static inline size_t align_up(size_t v, size_t a) { return (v + a - 1) & ~(a - 1); }

extern "C" void kernel_launch(void* const* d_in, const int* in_sizes, int n_in,
                              void* d_out, int out_size, void* d_ws, size_t ws_size,
                              hipStream_t stream) {
    const float* x  = (const float*)d_in[0];
    const int*   ei = (const int*)d_in[1];
    const float* W1 = (const float*)d_in[2];
    const float* b1 = (const float*)d_in[3];
    const float* W2 = (const float*)d_in[4];
    const float* b2 = (const float*)d_in[5];
    const float* W3 = (const float*)d_in[6];
    const float* b3 = (const float*)d_in[7];
    const float* W4 = (const float*)d_in[8];
    const float* b4 = (const float*)d_in[9];
    float* out = (float*)d_out;

    const int N = in_sizes[0] / 12;
    const int E = in_sizes[1] / 2;
    const int* src = ei;       // edge_index[0]
    const int* dst = ei + E;   // edge_index[1]
    const int NB = (N + NPB - 1) / NPB;  // 196

    // Workspace carve-up (~62 MB)
    char* ws = (char*)d_ws;
    size_t off = 0;
    int* bucket_cnt = (int*)(ws + off);   off = align_up(off + (size_t)NB * 4, 256);
    int* bucket_ptr = (int*)(ws + off);   off = align_up(off + (size_t)(NB + 1) * 4, 256);
    int* bucket_cur = (int*)(ws + off);   off = align_up(off + (size_t)NB * 4, 256);
    int* row_ptr = (int*)(ws + off);      off = align_up(off + (size_t)(N + 1) * 4, 256);
    float* dis = (float*)(ws + off);      off = align_up(off + (size_t)N * 4, 256);
    unsigned int* binned = (unsigned int*)(ws + off); off = align_up(off + (size_t)E * 4, 256);
    int* col = (int*)(ws + off);          off = align_up(off + (size_t)E * 4, 256);
    __half* xls = (__half*)(ws + off);    off = align_up(off + (size_t)N * 16 * 2, 256);
    float* agg = (float*)(ws + off);      off = align_up(off + (size_t)N * 16 * 4, 256);
    (void)ws_size; (void)n_in; (void)out_size;

    const int B = 256;
    auto blocks = [&](long long n) { return (int)((n + B - 1) / B); };
    int nb2 = blocks(2LL * N);          // ranges for merged gather
    nb2 = (nb2 + 3) & ~3;               // multiple of 4
    const int G2 = nb2 * 2;             // merged-gather grid (mult of 8)

    // --- CSR build via bucketed counting sort ----------------------------
    hipMemsetAsync(bucket_cnt, 0, (size_t)NB * sizeof(int), stream);
    hist_kernel<<<512, B, 0, stream>>>(dst, bucket_cnt, E, NB);
    bscan_kernel<<<1, 1024, 0, stream>>>(bucket_cnt, bucket_ptr, bucket_cur, row_ptr, NB, N, E);
    bin_kernel<<<(E + BIN_CHUNK - 1) / BIN_CHUNK, BIN_TH, 0, stream>>>(src, dst, bucket_cur, binned, E, NB);
    csr_bucket_kernel<<<NB * 2, 512, 0, stream>>>(binned, bucket_ptr, row_ptr, dis, col, N);

    // Chunk-table bases (half units): chunk c of size C lives at c*N*C
    __half* x_c0 = xls;
    __half* x_c8 = xls + (size_t)N * 8;  // second chunk for C=8 layers
    __half* x_c6 = xls + (size_t)N * 6;  // second chunk for C=6 layer

    // --- Layer 1: x(12) @ W1 -> 16 (chunks 2x8, merged gather) -----------
    transform_kernel<12, 16, 8, 0><<<blocks(N), B, 0, stream>>>(x, nullptr, W1, dis, xls, N);
    gather2_kernel<8, 16><<<G2, B, 0, stream>>>(row_ptr, col, dis, x_c0, x_c8, agg, N);

    // --- Layer 2: relu(agg + b1)(16) @ W2 -> 8 (1x8) ---------------------
    transform_kernel<16, 8, 8, 1><<<blocks(N), B, 0, stream>>>(agg, b1, W2, dis, xls, N);
    gather_kernel<8, 8, 0><<<blocks(2LL * N), B, 0, stream>>>(row_ptr, col, dis, x_c0, agg, N);

    // --- Layer 3: (agg + b2)(8) @ W3 -> 16 (2x8 merged, no relu) ---------
    transform_kernel<8, 16, 8, 2><<<blocks(N), B, 0, stream>>>(agg, b2, W3, dis, xls, N);
    gather2_kernel<8, 16><<<G2, B, 0, stream>>>(row_ptr, col, dis, x_c0, x_c8, agg, N);

    // --- Layer 4: relu(agg + b3)(16) @ W4 -> 12 (chunks 2x6, merged) -----
    transform_kernel<16, 12, 6, 1><<<blocks(N), B, 0, stream>>>(agg, b3, W4, dis, xls, N);
    gather2_kernel<6, 12><<<G2, B, 0, stream>>>(row_ptr, col, dis, x_c0, x_c6, agg, N);

    // --- Epilogue: sigmoid(agg + b4) -> out ------------------------------
    final_kernel<<<blocks((long long)N * 12), B, 0, stream>>>(agg, b4, out, N * 12, 12);
}